// Round 5
// baseline (380.843 us; speedup 1.0000x reference)
//
#include <hip/hip_runtime.h>

#define DEVI __device__ __forceinline__

static constexpr float KEPS = 1e-8f;

DEVI float frcp(float x) { return __builtin_amdgcn_rcpf(x); }
DEVI float frsq(float x) { return __builtin_amdgcn_rsqf(x); }

// One Jacobi rotation on symmetric 4x4 A (indices P<Q), accumulating into V.
template<int P, int Q>
DEVI void jrot(float A[4][4], float V[4][4]) {
  float apq = A[P][Q];
  if (fabsf(apq) > 1e-20f) {
    float theta = (A[Q][Q] - A[P][P]) * 0.5f * frcp(apq);
    float t = copysignf(frcp(fabsf(theta) + sqrtf(theta * theta + 1.0f)), theta);
    float c = frsq(t * t + 1.0f);
    float s = t * c;
#pragma unroll
    for (int k = 0; k < 4; ++k) { float u = A[k][P], v = A[k][Q]; A[k][P] = c*u - s*v; A[k][Q] = s*u + c*v; }
#pragma unroll
    for (int k = 0; k < 4; ++k) { float u = A[P][k], v = A[Q][k]; A[P][k] = c*u - s*v; A[Q][k] = s*u + c*v; }
#pragma unroll
    for (int k = 0; k < 4; ++k) { float u = V[k][P], v = V[k][Q]; V[k][P] = c*u - s*v; V[k][Q] = s*u + c*v; }
  }
}

// Rotate child joint C about pivot (px,py,pz) by r.
template<int C>
DEVI void rotc(float t[21][3], float px, float py, float pz,
               float r00, float r01, float r02,
               float r10, float r11, float r12,
               float r20, float r21, float r22) {
  float x = t[C][0] - px, y = t[C][1] - py, z = t[C][2] - pz;
  t[C][0] = r00*x + r01*y + r02*z + px;
  t[C][1] = r10*x + r11*y + r12*z + py;
  t[C][2] = r20*x + r21*y + r22*z + pz;
}

// One twist step: align bone (PI -> I) toward target g[I]-t[PI]; rotate NC children.
template<int PI, int I, int C0, int C1, int C2, int NC>
DEVI void bone(float t[21][3], const float g[21][3]) {
  float px = t[PI][0], py = t[PI][1], pz = t[PI][2];
  float v0x = t[I][0] - px, v0y = t[I][1] - py, v0z = t[I][2] - pz;
  float v1x = g[I][0] - px, v1y = g[I][1] - py, v1z = g[I][2] - pz;
  float in0 = frcp(sqrtf(v0x*v0x + v0y*v0y + v0z*v0z) + KEPS);
  float in1 = frcp(sqrtf(v1x*v1x + v1y*v1y + v1z*v1z) + KEPS);
  float ax = v0x*in0, ay = v0y*in0, az = v0z*in0;
  float bx = v1x*in1, by = v1y*in1, bz = v1z*in1;
  float c = ax*bx + ay*by + az*bz;
  float cx = ay*bz - az*by;
  float cy = az*bx - ax*bz;
  float cz = ax*by - ay*bx;
  float s = sqrtf(cx*cx + cy*cy + cz*cz);
  float is = frcp(s + KEPS);
  float kx = cx*is, ky = cy*is, kz = cz*is;
  float omc = 1.0f - c;
  float r00 = 1.0f - omc*(ky*ky + kz*kz);
  float r11 = 1.0f - omc*(kx*kx + kz*kz);
  float r22 = 1.0f - omc*(kx*kx + ky*ky);
  float kxy = omc*kx*ky, kxz = omc*kx*kz, kyz = omc*ky*kz;
  float skx = s*kx, sky = s*ky, skz = s*kz;
  float r01 = kxy - skz, r10 = kxy + skz;
  float r02 = kxz + sky, r20 = kxz - sky;
  float r12 = kyz - skx, r21 = kyz + skx;
  rotc<C0>(t, px, py, pz, r00, r01, r02, r10, r11, r12, r20, r21, r22);
  if constexpr (NC > 1) rotc<C1>(t, px, py, pz, r00, r01, r02, r10, r11, r12, r20, r21, r22);
  if constexpr (NC > 2) rotc<C2>(t, px, py, pz, r00, r01, r02, r10, r11, r12, r20, r21, r22);
}

// Finger chain: base joint B, B+1, B+2, tip T.
template<int B, int T>
DEVI void finger(float t[21][3], const float g[21][3]) {
  bone<B,     B + 1, B + 1, B + 2, T, 3>(t, g);
  bone<B + 1, B + 2, B + 2, T,     T, 2>(t, g);
  bone<B + 2, T,     T,     T,     T, 1>(t, g);
}

// 4 waves / WG, each wave fully independent: private 4KB LDS quarter,
// stages its 64 items in four 16-item rounds. NO __syncthreads anywhere.
__global__ void __launch_bounds__(256, 4)
kin_kernel(const float* __restrict__ joint_gt, const float* __restrict__ tempJ,
           float* __restrict__ out, int N) {
  __shared__ float lds[4][16 * 63];   // 16128 B total
  const int wave = threadIdx.x >> 6;
  const int lane = threadIdx.x & 63;
  float* buf = &lds[wave][0];
  const long long item0 = ((long long)blockIdx.x * 4 + wave) * 64;
  if (item0 >= N) return;            // safe: no barriers in this kernel
  const bool wfull = (item0 + 64) <= (long long)N;
  const long long total = (long long)N * 63;

  float t[21][3], g[21][3];
  float wx, wy, wz;

  // ---- stage tempJ: 4 rounds x 16 items into private 4KB; owning 16 lanes unpack ----
#pragma unroll 1
  for (int r = 0; r < 4; ++r) {
    const long long off = (item0 + r * 16) * 63;
    if (wfull) {
      const float4* s4 = (const float4*)(tempJ + off);
#pragma unroll
      for (int k = 0; k < 4; ++k) { int i = k * 64 + lane; if (i < 252) ((float4*)buf)[i] = s4[i]; }
    } else {
      for (int i = lane; i < 1008; i += 64) { long long gi = off + i; buf[i] = (gi < total) ? tempJ[gi] : 0.0f; }
    }
    if ((lane >> 4) == r) {
      const float* p = buf + (lane & 15) * 63;
      float rx = p[0], ry = p[1], rz = p[2];
#pragma unroll
      for (int j = 0; j < 21; ++j) {
        t[j][0] = p[3 * j + 0] - rx;
        t[j][1] = p[3 * j + 1] - ry;
        t[j][2] = p[3 * j + 2] - rz;
      }
    }
  }

  // ---- stage joint_gt the same way ----
#pragma unroll 1
  for (int r = 0; r < 4; ++r) {
    const long long off = (item0 + r * 16) * 63;
    if (wfull) {
      const float4* s4 = (const float4*)(joint_gt + off);
#pragma unroll
      for (int k = 0; k < 4; ++k) { int i = k * 64 + lane; if (i < 252) ((float4*)buf)[i] = s4[i]; }
    } else {
      for (int i = lane; i < 1008; i += 64) { long long gi = off + i; buf[i] = (gi < total) ? joint_gt[gi] : 0.0f; }
    }
    if ((lane >> 4) == r) {
      const float* p = buf + (lane & 15) * 63;
      wx = p[0]; wy = p[1]; wz = p[2];
#pragma unroll
      for (int j = 0; j < 21; ++j) {
        g[j][0] = p[3 * j + 0] - wx;
        g[j][1] = p[3 * j + 1] - wy;
        g[j][2] = p[3 * j + 2] - wz;
      }
    }
  }

  // ---- H = tJ0^T @ jg (3x3 correlation) ----
  float H[3][3] = {{0, 0, 0}, {0, 0, 0}, {0, 0, 0}};
#pragma unroll
  for (int j = 0; j < 21; ++j)
#pragma unroll
    for (int a = 0; a < 3; ++a)
#pragma unroll
      for (int b = 0; b < 3; ++b)
        H[a][b] += t[j][a] * g[j][b];

  // ---- Horn's 4x4 N matrix; Jacobi eigensolver; max-eigenvector quaternion ----
  float Sxx = H[0][0], Sxy = H[0][1], Sxz = H[0][2];
  float Syx = H[1][0], Syy = H[1][1], Syz = H[1][2];
  float Szx = H[2][0], Szy = H[2][1], Szz = H[2][2];
  float A[4][4] = {
    {  Sxx + Syy + Szz, Syz - Szy,        Szx - Sxz,        Sxy - Syx },
    {  Syz - Szy,       Sxx - Syy - Szz,  Sxy + Syx,        Szx + Sxz },
    {  Szx - Sxz,       Sxy + Syx,       -Sxx + Syy - Szz,  Syz + Szy },
    {  Sxy - Syx,       Szx + Sxz,        Syz + Szy,       -Sxx - Syy + Szz }};
  float V[4][4] = {{1,0,0,0},{0,1,0,0},{0,0,1,0},{0,0,0,1}};
  // unroll 1: eigensolver code footprint stays 6x smaller (I$ fit — R1's measured win).
#pragma unroll 1
  for (int sw = 0; sw < 6; ++sw) {
    jrot<0,1>(A, V); jrot<0,2>(A, V); jrot<0,3>(A, V);
    jrot<1,2>(A, V); jrot<1,3>(A, V); jrot<2,3>(A, V);
  }
  float e  = A[0][0];
  float qw = V[0][0], qx = V[1][0], qy = V[2][0], qz = V[3][0];
#define PICK(K) { bool bb = A[K][K] > e; e = bb ? A[K][K] : e; \
  qw = bb ? V[0][K] : qw; qx = bb ? V[1][K] : qx; qy = bb ? V[2][K] : qy; qz = bb ? V[3][K] : qz; }
  PICK(1) PICK(2) PICK(3)
#undef PICK
  float qn = frsq(qw*qw + qx*qx + qy*qy + qz*qz);
  qw *= qn; qx *= qn; qy *= qn; qz *= qn;
  float R00 = 1.0f - 2.0f*(qy*qy + qz*qz), R01 = 2.0f*(qx*qy - qw*qz), R02 = 2.0f*(qx*qz + qw*qy);
  float R10 = 2.0f*(qx*qy + qw*qz), R11 = 1.0f - 2.0f*(qx*qx + qz*qz), R12 = 2.0f*(qy*qz - qw*qx);
  float R20 = 2.0f*(qx*qz - qw*qy), R21 = 2.0f*(qy*qz + qw*qx), R22 = 1.0f - 2.0f*(qx*qx + qy*qy);

  // ---- tJ = Rw @ tJ0 ----
#pragma unroll
  for (int j = 1; j < 21; ++j) {
    float x = t[j][0], y = t[j][1], z = t[j][2];
    t[j][0] = R00*x + R01*y + R02*z;
    t[j][1] = R10*x + R11*y + R12*z;
    t[j][2] = R20*x + R21*y + R22*z;
  }

  // ---- 15 twist alignments (output == final tJ; FK is algebraically identical) ----
  finger<1, 17>(t, g);
  finger<4, 18>(t, g);
  finger<7, 20>(t, g);
  finger<10, 19>(t, g);
  finger<13, 16>(t, g);

  // ---- registers -> private LDS (16 items/round) -> coalesced float4 store ----
#pragma unroll 1
  for (int r = 0; r < 4; ++r) {
    if ((lane >> 4) == r) {
      float* p = buf + (lane & 15) * 63;
#pragma unroll
      for (int j = 0; j < 21; ++j) {
        p[3 * j + 0] = t[j][0] + wx;
        p[3 * j + 1] = t[j][1] + wy;
        p[3 * j + 2] = t[j][2] + wz;
      }
    }
    const long long off = (item0 + r * 16) * 63;
    if (wfull) {
      float4* d4 = (float4*)(out + off);
#pragma unroll
      for (int k = 0; k < 4; ++k) { int i = k * 64 + lane; if (i < 252) d4[i] = ((const float4*)buf)[i]; }
    } else {
      for (int i = lane; i < 1008; i += 64) { long long gi = off + i; if (gi < total) out[gi] = buf[i]; }
    }
  }
}

extern "C" void kernel_launch(void* const* d_in, const int* in_sizes, int n_in,
                              void* d_out, int out_size, void* d_ws, size_t ws_size,
                              hipStream_t stream) {
  const float* joint_gt = (const float*)d_in[0];
  const float* tempJ    = (const float*)d_in[1];
  float* out = (float*)d_out;
  int N = in_sizes[0] / 63;
  int waves = (N + 63) / 64;
  int blocks = (waves + 3) / 4;
  hipLaunchKernelGGL(kin_kernel, dim3(blocks), dim3(256), 0, stream,
                     joint_gt, tempJ, out, N);
}

// Round 6
// 313.705 us; speedup vs baseline: 1.2140x; 1.2140x over previous
//
#include <hip/hip_runtime.h>

#define DEVI __device__ __forceinline__

static constexpr float KEPS = 1e-8f;

DEVI float frcp(float x) { return __builtin_amdgcn_rcpf(x); }
DEVI float frsq(float x) { return __builtin_amdgcn_rsqf(x); }

// One Jacobi rotation on symmetric 4x4 A (indices P<Q), accumulating into V.
template<int P, int Q>
DEVI void jrot(float A[4][4], float V[4][4]) {
  float apq = A[P][Q];
  if (fabsf(apq) > 1e-20f) {
    float theta = (A[Q][Q] - A[P][P]) * 0.5f * frcp(apq);
    float t = copysignf(frcp(fabsf(theta) + sqrtf(theta * theta + 1.0f)), theta);
    float c = frsq(t * t + 1.0f);
    float s = t * c;
#pragma unroll
    for (int k = 0; k < 4; ++k) { float u = A[k][P], v = A[k][Q]; A[k][P] = c*u - s*v; A[k][Q] = s*u + c*v; }
#pragma unroll
    for (int k = 0; k < 4; ++k) { float u = A[P][k], v = A[Q][k]; A[P][k] = c*u - s*v; A[Q][k] = s*u + c*v; }
#pragma unroll
    for (int k = 0; k < 4; ++k) { float u = V[k][P], v = V[k][Q]; V[k][P] = c*u - s*v; V[k][Q] = s*u + c*v; }
  }
}

// Rotate child joint C about pivot (px,py,pz) by r.
template<int C>
DEVI void rotc(float t[21][3], float px, float py, float pz,
               float r00, float r01, float r02,
               float r10, float r11, float r12,
               float r20, float r21, float r22) {
  float x = t[C][0] - px, y = t[C][1] - py, z = t[C][2] - pz;
  t[C][0] = r00*x + r01*y + r02*z + px;
  t[C][1] = r10*x + r11*y + r12*z + py;
  t[C][2] = r20*x + r21*y + r22*z + pz;
}

// One twist step: align bone (PI -> I) toward target g[I]-t[PI]; rotate NC children.
template<int PI, int I, int C0, int C1, int C2, int NC>
DEVI void bone(float t[21][3], const float g[21][3]) {
  float px = t[PI][0], py = t[PI][1], pz = t[PI][2];
  float v0x = t[I][0] - px, v0y = t[I][1] - py, v0z = t[I][2] - pz;
  float v1x = g[I][0] - px, v1y = g[I][1] - py, v1z = g[I][2] - pz;
  float in0 = frcp(sqrtf(v0x*v0x + v0y*v0y + v0z*v0z) + KEPS);
  float in1 = frcp(sqrtf(v1x*v1x + v1y*v1y + v1z*v1z) + KEPS);
  float ax = v0x*in0, ay = v0y*in0, az = v0z*in0;
  float bx = v1x*in1, by = v1y*in1, bz = v1z*in1;
  float c = ax*bx + ay*by + az*bz;
  float cx = ay*bz - az*by;
  float cy = az*bx - ax*bz;
  float cz = ax*by - ay*bx;
  float s = sqrtf(cx*cx + cy*cy + cz*cz);
  float is = frcp(s + KEPS);
  float kx = cx*is, ky = cy*is, kz = cz*is;
  float omc = 1.0f - c;
  float r00 = 1.0f - omc*(ky*ky + kz*kz);
  float r11 = 1.0f - omc*(kx*kx + kz*kz);
  float r22 = 1.0f - omc*(kx*kx + ky*ky);
  float kxy = omc*kx*ky, kxz = omc*kx*kz, kyz = omc*ky*kz;
  float skx = s*kx, sky = s*ky, skz = s*kz;
  float r01 = kxy - skz, r10 = kxy + skz;
  float r02 = kxz + sky, r20 = kxz - sky;
  float r12 = kyz - skx, r21 = kyz + skx;
  rotc<C0>(t, px, py, pz, r00, r01, r02, r10, r11, r12, r20, r21, r22);
  if constexpr (NC > 1) rotc<C1>(t, px, py, pz, r00, r01, r02, r10, r11, r12, r20, r21, r22);
  if constexpr (NC > 2) rotc<C2>(t, px, py, pz, r00, r01, r02, r10, r11, r12, r20, r21, r22);
}

// Finger chain: base joint B, B+1, B+2, tip T.
template<int B, int T>
DEVI void finger(float t[21][3], const float g[21][3]) {
  bone<B,     B + 1, B + 1, B + 2, T, 3>(t, g);
  bone<B + 1, B + 2, B + 2, T,     T, 2>(t, g);
  bone<B + 2, T,     T,     T,     T, 1>(t, g);
}

// 4 waves / WG, each wave fully independent: private 4KB LDS quarter,
// stages its 64 items in four 16-item rounds. NO __syncthreads anywhere.
// NOTE: no min-waves hint — R5 showed (256,4) forces VGPR=64 and spills t/g
// to scratch (+400MB HBM). Natural allocation is ~120-128 VGPR -> 16 waves/CU.
__global__ void __launch_bounds__(256)
kin_kernel(const float* __restrict__ joint_gt, const float* __restrict__ tempJ,
           float* __restrict__ out, int N) {
  __shared__ float lds[4][16 * 63];   // 16128 B total
  const int wave = threadIdx.x >> 6;
  const int lane = threadIdx.x & 63;
  float* buf = &lds[wave][0];
  const long long item0 = ((long long)blockIdx.x * 4 + wave) * 64;
  if (item0 >= N) return;            // safe: no barriers in this kernel
  const bool wfull = (item0 + 64) <= (long long)N;
  const long long total = (long long)N * 63;

  float t[21][3], g[21][3];
  float wx, wy, wz;

  // ---- stage tempJ: 4 rounds x 16 items into private 4KB; owning 16 lanes unpack ----
#pragma unroll 1
  for (int r = 0; r < 4; ++r) {
    const long long off = (item0 + r * 16) * 63;
    if (wfull) {
      const float4* s4 = (const float4*)(tempJ + off);
#pragma unroll
      for (int k = 0; k < 4; ++k) { int i = k * 64 + lane; if (i < 252) ((float4*)buf)[i] = s4[i]; }
    } else {
      for (int i = lane; i < 1008; i += 64) { long long gi = off + i; buf[i] = (gi < total) ? tempJ[gi] : 0.0f; }
    }
    if ((lane >> 4) == r) {
      const float* p = buf + (lane & 15) * 63;
      float rx = p[0], ry = p[1], rz = p[2];
#pragma unroll
      for (int j = 0; j < 21; ++j) {
        t[j][0] = p[3 * j + 0] - rx;
        t[j][1] = p[3 * j + 1] - ry;
        t[j][2] = p[3 * j + 2] - rz;
      }
    }
  }

  // ---- stage joint_gt the same way ----
#pragma unroll 1
  for (int r = 0; r < 4; ++r) {
    const long long off = (item0 + r * 16) * 63;
    if (wfull) {
      const float4* s4 = (const float4*)(joint_gt + off);
#pragma unroll
      for (int k = 0; k < 4; ++k) { int i = k * 64 + lane; if (i < 252) ((float4*)buf)[i] = s4[i]; }
    } else {
      for (int i = lane; i < 1008; i += 64) { long long gi = off + i; buf[i] = (gi < total) ? joint_gt[gi] : 0.0f; }
    }
    if ((lane >> 4) == r) {
      const float* p = buf + (lane & 15) * 63;
      wx = p[0]; wy = p[1]; wz = p[2];
#pragma unroll
      for (int j = 0; j < 21; ++j) {
        g[j][0] = p[3 * j + 0] - wx;
        g[j][1] = p[3 * j + 1] - wy;
        g[j][2] = p[3 * j + 2] - wz;
      }
    }
  }

  // ---- H = tJ0^T @ jg (3x3 correlation) ----
  float H[3][3] = {{0, 0, 0}, {0, 0, 0}, {0, 0, 0}};
#pragma unroll
  for (int j = 0; j < 21; ++j)
#pragma unroll
    for (int a = 0; a < 3; ++a)
#pragma unroll
      for (int b = 0; b < 3; ++b)
        H[a][b] += t[j][a] * g[j][b];

  // ---- Horn's 4x4 N matrix; Jacobi eigensolver; max-eigenvector quaternion ----
  float Sxx = H[0][0], Sxy = H[0][1], Sxz = H[0][2];
  float Syx = H[1][0], Syy = H[1][1], Syz = H[1][2];
  float Szx = H[2][0], Szy = H[2][1], Szz = H[2][2];
  float A[4][4] = {
    {  Sxx + Syy + Szz, Syz - Szy,        Szx - Sxz,        Sxy - Syx },
    {  Syz - Szy,       Sxx - Syy - Szz,  Sxy + Syx,        Szx + Sxz },
    {  Szx - Sxz,       Sxy + Syx,       -Sxx + Syy - Szz,  Syz + Szy },
    {  Sxy - Syx,       Szx + Sxz,        Syz + Szy,       -Sxx - Syy + Szz }};
  float V[4][4] = {{1,0,0,0},{0,1,0,0},{0,0,1,0},{0,0,0,1}};
  // unroll 1: eigensolver code footprint stays 6x smaller (I$ fit — R1's measured win).
#pragma unroll 1
  for (int sw = 0; sw < 6; ++sw) {
    jrot<0,1>(A, V); jrot<0,2>(A, V); jrot<0,3>(A, V);
    jrot<1,2>(A, V); jrot<1,3>(A, V); jrot<2,3>(A, V);
  }
  float e  = A[0][0];
  float qw = V[0][0], qx = V[1][0], qy = V[2][0], qz = V[3][0];
#define PICK(K) { bool bb = A[K][K] > e; e = bb ? A[K][K] : e; \
  qw = bb ? V[0][K] : qw; qx = bb ? V[1][K] : qx; qy = bb ? V[2][K] : qy; qz = bb ? V[3][K] : qz; }
  PICK(1) PICK(2) PICK(3)
#undef PICK
  float qn = frsq(qw*qw + qx*qx + qy*qy + qz*qz);
  qw *= qn; qx *= qn; qy *= qn; qz *= qn;
  float R00 = 1.0f - 2.0f*(qy*qy + qz*qz), R01 = 2.0f*(qx*qy - qw*qz), R02 = 2.0f*(qx*qz + qw*qy);
  float R10 = 2.0f*(qx*qy + qw*qz), R11 = 1.0f - 2.0f*(qx*qx + qz*qz), R12 = 2.0f*(qy*qz - qw*qx);
  float R20 = 2.0f*(qx*qz - qw*qy), R21 = 2.0f*(qy*qz + qw*qx), R22 = 1.0f - 2.0f*(qx*qx + qy*qy);

  // ---- tJ = Rw @ tJ0 ----
#pragma unroll
  for (int j = 1; j < 21; ++j) {
    float x = t[j][0], y = t[j][1], z = t[j][2];
    t[j][0] = R00*x + R01*y + R02*z;
    t[j][1] = R10*x + R11*y + R12*z;
    t[j][2] = R20*x + R21*y + R22*z;
  }

  // ---- 15 twist alignments (output == final tJ; FK is algebraically identical) ----
  finger<1, 17>(t, g);
  finger<4, 18>(t, g);
  finger<7, 20>(t, g);
  finger<10, 19>(t, g);
  finger<13, 16>(t, g);

  // ---- registers -> private LDS (16 items/round) -> coalesced float4 store ----
#pragma unroll 1
  for (int r = 0; r < 4; ++r) {
    if ((lane >> 4) == r) {
      float* p = buf + (lane & 15) * 63;
#pragma unroll
      for (int j = 0; j < 21; ++j) {
        p[3 * j + 0] = t[j][0] + wx;
        p[3 * j + 1] = t[j][1] + wy;
        p[3 * j + 2] = t[j][2] + wz;
      }
    }
    const long long off = (item0 + r * 16) * 63;
    if (wfull) {
      float4* d4 = (float4*)(out + off);
#pragma unroll
      for (int k = 0; k < 4; ++k) { int i = k * 64 + lane; if (i < 252) d4[i] = ((const float4*)buf)[i]; }
    } else {
      for (int i = lane; i < 1008; i += 64) { long long gi = off + i; if (gi < total) out[gi] = buf[i]; }
    }
  }
}

extern "C" void kernel_launch(void* const* d_in, const int* in_sizes, int n_in,
                              void* d_out, int out_size, void* d_ws, size_t ws_size,
                              hipStream_t stream) {
  const float* joint_gt = (const float*)d_in[0];
  const float* tempJ    = (const float*)d_in[1];
  float* out = (float*)d_out;
  int N = in_sizes[0] / 63;
  int waves = (N + 63) / 64;
  int blocks = (waves + 3) / 4;
  hipLaunchKernelGGL(kin_kernel, dim3(blocks), dim3(256), 0, stream,
                     joint_gt, tempJ, out, N);
}